// Round 8
// baseline (196.175 us; speedup 1.0000x reference)
//
#include <hip/hip_runtime.h>
#include <hip/hip_bf16.h>
#include <math.h>

// B=1, C=32, H=D=W=32, N=32768, modes 16^3 (z 0..15 of 17), KS=3, MEM=5
#define NSP 32768
#define NZ 17

__device__ __forceinline__ float geluf(float x){
    return 0.5f * x * (1.0f + erff(x * 0.70710678118654752f));
}
__device__ __forceinline__ float sigmoidf_(float x){
    return 1.0f / (1.0f + __expf(-x));
}

// ---------------- FFT stages (direct DFT-32) ----------------

// fused rfft along W + fft along D. x: (C,H,D,W). out Br/Bi: (C,H,Dk,17). block per (c*32+h)
__global__ void k_fwd(const float* __restrict__ x, float* __restrict__ Br, float* __restrict__ Bi){
    __shared__ float tile[32*33];
    __shared__ float ar[544], ai[544];
    __shared__ float ct[32], st[32];
    int b = blockIdx.x, t = threadIdx.x;
    if (t < 32){ float ang = 6.283185307179586477f * (float)t / 32.0f; ct[t] = cosf(ang); st[t] = sinf(ang); }
    const float* src = x + b * 1024;
    for (int j = t; j < 1024; j += 256) tile[(j & 31) * 33 + (j >> 5)] = src[j];
    __syncthreads();
    for (int idx = t; idx < 544; idx += 256){
        int d = idx / 17, z = idx - d * 17;
        float sr = 0.f, si = 0.f;
        #pragma unroll
        for (int w = 0; w < 32; ++w){
            int a = (z * w) & 31;
            float v = tile[w * 33 + d];
            sr += v * ct[a];
            si -= v * st[a];
        }
        ar[idx] = sr; ai[idx] = si;
    }
    __syncthreads();
    for (int idx = t; idx < 544; idx += 256){
        int kd = idx / 17, z = idx - kd * 17;
        float sr = 0.f, si = 0.f;
        #pragma unroll
        for (int d = 0; d < 32; ++d){
            int a = (kd * d) & 31;
            float c = ct[a], s = st[a];
            float vr = ar[d * 17 + z], vi = ai[d * 17 + z];
            sr += vr * c + vi * s;      // e^{-i}
            si += vi * c - vr * s;
        }
        Br[b * 544 + idx] = sr; Bi[b * 544 + idx] = si;
    }
}

// forward fft along H: gather h-strided. block per (c*32+d). out (C,Hk,Dk,17)
__global__ void k_fft_h(const float* __restrict__ Br, const float* __restrict__ Bi,
                        float* __restrict__ Ar, float* __restrict__ Ai){
    __shared__ float ir[544], ii[544];
    __shared__ float ct[32], st[32];
    int b = blockIdx.x, t = threadIdx.x;
    int c = b >> 5, d = b & 31;
    if (t < 32){ float ang = 6.283185307179586477f * (float)t / 32.0f; ct[t] = cosf(ang); st[t] = sinf(ang); }
    for (int j = t; j < 544; j += 256){
        int h = j / 17, z = j - h * 17;
        int g = ((c * 32 + h) * 32 + d) * NZ + z;
        ir[j] = Br[g]; ii[j] = Bi[g];
    }
    __syncthreads();
    for (int idx = t; idx < 544; idx += 256){
        int kh = idx / 17, z = idx - kh * 17;
        float sr = 0.f, si = 0.f;
        #pragma unroll
        for (int h = 0; h < 32; ++h){
            int a = (kh * h) & 31;
            float c2 = ct[a], s2 = st[a];
            float vr = ir[h * 17 + z], vi = ii[h * 17 + z];
            sr += vr * c2 + vi * s2;
            si += vi * c2 - vr * s2;
        }
        int g = ((c * 32 + kh) * 32 + d) * NZ + z;
        Ar[g] = sr; Ai[g] = si;
    }
}

// spectral multiply. Xr/Xi: (C,Hk,Dk,17). W: (4,Ci,Co,16,16,16). Out Or/Oi, z=16 zeroed.
// 512 blocks = (corner, og of 4 o's, xm). 256 threads = 4 waves; wave = one o;
// lane handles 4 consecutive modes -> float4 weight loads (1KB per wave-load).
__global__ void k_modemul(const float* __restrict__ Xr, const float* __restrict__ Xi,
                          const float* __restrict__ Wr, const float* __restrict__ Wi,
                          float* __restrict__ Or, float* __restrict__ Oi){
    __shared__ float xr[32][256], xi[32][256];
    int b = blockIdx.x;
    int corner = b >> 7;          // 0..3
    int og = (b >> 4) & 7;        // 0..7
    int xm = b & 15;              // 0..15
    int xg = xm + ((corner & 1) << 4);
    int ybase = (corner >> 1) << 4;
    int t = threadIdx.x;
    // stage x tile: 32 i x 256 modes (shared by the 4 waves / 4 o's)
    for (int idx = t; idx < 8192; idx += 256){
        int i = idx >> 8, mm = idx & 255;
        int y = ybase + (mm >> 4), z = mm & 15;
        int g = ((i * 32 + xg) * 32 + y) * NZ + z;
        xr[i][mm] = Xr[g]; xi[i][mm] = Xi[g];
    }
    // zero z=16 plane for this block's (xg, y-range, o-range)
    if (t < 64){
        int o = og * 4 + (t >> 4), y = ybase + (t & 15);
        int g = ((o * 32 + xg) * 32 + y) * NZ + 16;
        Or[g] = 0.f; Oi[g] = 0.f;
    }
    __syncthreads();
    int wv = t >> 6, lane = t & 63;
    int o = og * 4 + wv;
    int m4 = lane * 4;
    const float* wrbase = Wr + (size_t)((corner * 32) * 32 + o) * 4096 + xm * 256 + m4;
    const float* wibase = Wi + (size_t)((corner * 32) * 32 + o) * 4096 + xm * 256 + m4;
    float4 accr = make_float4(0.f, 0.f, 0.f, 0.f);
    float4 acci = make_float4(0.f, 0.f, 0.f, 0.f);
    #pragma unroll 8
    for (int i = 0; i < 32; ++i){
        float4 w4r = *(const float4*)(wrbase + (size_t)i * 32 * 4096);
        float4 w4i = *(const float4*)(wibase + (size_t)i * 32 * 4096);
        float4 x4r = *(const float4*)(&xr[i][m4]);
        float4 x4i = *(const float4*)(&xi[i][m4]);
        accr.x += w4r.x * x4r.x - w4i.x * x4i.x;  acci.x += w4r.x * x4i.x + w4i.x * x4r.x;
        accr.y += w4r.y * x4r.y - w4i.y * x4i.y;  acci.y += w4r.y * x4i.y + w4i.y * x4r.y;
        accr.z += w4r.z * x4r.z - w4i.z * x4i.z;  acci.z += w4r.z * x4i.z + w4i.z * x4r.z;
        accr.w += w4r.w * x4r.w - w4i.w * x4i.w;  acci.w += w4r.w * x4i.w + w4i.w * x4r.w;
    }
    int y = ybase + (m4 >> 4), zm = m4 & 15;
    int gb = ((o * 32 + xg) * 32 + y) * NZ + zm;
    Or[gb + 0] = accr.x; Or[gb + 1] = accr.y; Or[gb + 2] = accr.z; Or[gb + 3] = accr.w;
    Oi[gb + 0] = acci.x; Oi[gb + 1] = acci.y; Oi[gb + 2] = acci.z; Oi[gb + 3] = acci.w;
}

// inverse fft along H. block per (c*32+y). in (C,Hk,Dk,17) -> (C,H,Dk,17)
__global__ void k_ifft_h(const float* __restrict__ Br, const float* __restrict__ Bi,
                         float* __restrict__ Ar, float* __restrict__ Ai){
    __shared__ float ir[544], ii[544];
    __shared__ float ct[32], st[32];
    int b = blockIdx.x, t = threadIdx.x;
    int c = b >> 5, y = b & 31;
    if (t < 32){ float ang = 6.283185307179586477f * (float)t / 32.0f; ct[t] = cosf(ang); st[t] = sinf(ang); }
    for (int j = t; j < 544; j += 256){
        int xk = j / 17, z = j - xk * 17;
        int g = ((c * 32 + xk) * 32 + y) * NZ + z;
        ir[j] = Br[g]; ii[j] = Bi[g];
    }
    __syncthreads();
    for (int idx = t; idx < 544; idx += 256){
        int h = idx / 17, z = idx - h * 17;
        float sr = 0.f, si = 0.f;
        #pragma unroll
        for (int k = 0; k < 32; ++k){
            int a = (k * h) & 31;
            float c2 = ct[a], s2 = st[a];
            float vr = ir[k * 17 + z], vi = ii[k * 17 + z];
            sr += vr * c2 - vi * s2;    // e^{+i}
            si += vr * s2 + vi * c2;
        }
        int g = ((c * 32 + h) * 32 + y) * NZ + z;
        Ar[g] = sr; Ai[g] = si;
    }
}

// fused inverse fft along D + irfft along W + GN1 stat partials. block per (c*32+h).
__global__ void k_inv(const float* __restrict__ Ar, const float* __restrict__ Ai,
                      float* __restrict__ spec,
                      float* __restrict__ psum, float* __restrict__ psq){
    __shared__ float ir[544], ii[544];
    __shared__ float cr[544], ci[544];
    __shared__ float ct[32], st[32];
    __shared__ float ls[256], lq[256];
    int b = blockIdx.x, t = threadIdx.x;
    if (t < 32){ float ang = 6.283185307179586477f * (float)t / 32.0f; ct[t] = cosf(ang); st[t] = sinf(ang); }
    const float* pr = Ar + b * 544;
    const float* pi = Ai + b * 544;
    for (int j = t; j < 544; j += 256){ ir[j] = pr[j]; ii[j] = pi[j]; }
    __syncthreads();
    for (int idx = t; idx < 544; idx += 256){
        int d = idx / 17, z = idx - d * 17;
        float sr = 0.f, si = 0.f;
        #pragma unroll
        for (int k = 0; k < 32; ++k){
            int a = (k * d) & 31;
            float c2 = ct[a], s2 = st[a];
            float vr = ir[k * 17 + z], vi = ii[k * 17 + z];
            sr += vr * c2 - vi * s2;
            si += vr * s2 + vi * c2;
        }
        cr[idx] = sr; ci[idx] = si;
    }
    __syncthreads();
    const float inv = 1.0f / 32768.0f;
    float s_loc = 0.f, q_loc = 0.f;
    for (int idx = t; idx < 1024; idx += 256){
        int d = idx >> 5, w = idx & 31;
        float s = cr[d * 17 + 0] + ((w & 1) ? -cr[d * 17 + 16] : cr[d * 17 + 16]);
        #pragma unroll
        for (int z = 1; z < 16; ++z){
            int a = (z * w) & 31;
            s += 2.0f * (cr[d * 17 + z] * ct[a] - ci[d * 17 + z] * st[a]);
        }
        s *= inv;
        spec[b * 1024 + idx] = s;
        s_loc += s; q_loc += s * s;
    }
    ls[t] = s_loc; lq[t] = q_loc; __syncthreads();
    for (int off = 128; off > 0; off >>= 1){
        if (t < off){ ls[t] += ls[t + off]; lq[t] += lq[t + off]; }
        __syncthreads();
    }
    if (t == 0){ psum[b] = ls[0]; psq[b] = lq[0]; }
}

// ---------------- reductions / elementwise ----------------

__global__ void k_finalize1(const float* __restrict__ psum, const float* __restrict__ psq,
                            int n, float* __restrict__ red){
    __shared__ float ls[256], lq[256];
    int t = threadIdx.x;
    float s = 0.f, q = 0.f;
    for (int j = t; j < n; j += 256){ s += psum[j]; q += psq[j]; }
    ls[t] = s; lq[t] = q; __syncthreads();
    for (int off = 128; off > 0; off >>= 1){
        if (t < off){ ls[t] += ls[t + off]; lq[t] += lq[t + off]; }
        __syncthreads();
    }
    if (t == 0){
        float mu = ls[0] * (1.0f / 1048576.0f);
        float var = lq[0] * (1.0f / 1048576.0f) - mu * mu;
        red[0] = mu; red[1] = rsqrtf(var + 1e-5f);
    }
}

// GN2 finalize + gamma/beta from t
__global__ void k_finalize2(const float* __restrict__ psum, const float* __restrict__ psq,
                            int n, const float* __restrict__ tin,
                            const float* __restrict__ tgw, const float* __restrict__ tgb,
                            const float* __restrict__ tbw, const float* __restrict__ tbb,
                            float* __restrict__ red){
    __shared__ float ls[256], lq[256];
    int t = threadIdx.x;
    float s = 0.f, q = 0.f;
    for (int j = t; j < n; j += 256){ s += psum[j]; q += psq[j]; }
    ls[t] = s; lq[t] = q; __syncthreads();
    for (int off = 128; off > 0; off >>= 1){
        if (t < off){ ls[t] += ls[t + off]; lq[t] += lq[t + off]; }
        __syncthreads();
    }
    if (t == 0){
        float mu = ls[0] * (1.0f / 1048576.0f);
        float var = lq[0] * (1.0f / 1048576.0f) - mu * mu;
        red[2] = mu; red[3] = rsqrtf(var + 1e-5f);
    }
    if (t < 64){
        int o = t & 31;
        const float* w = (t < 32) ? tgw : tbw;
        const float* bi = (t < 32) ? tgb : tbb;
        float a = bi[o];
        #pragma unroll
        for (int c = 0; c < 32; ++c) a += w[o * 32 + c] * tin[c];
        red[(t < 32 ? 16 : 48) + o] = a;
    }
}

// fused GN1-apply + pointwise MLP (32 -> 16 gelu -> 32) + GN2 stat partials. thread per n.
__global__ void k_mlp(const float* __restrict__ spec, const float* __restrict__ x,
                      const float* __restrict__ n1g, const float* __restrict__ n1b,
                      const float* __restrict__ red,
                      const float* __restrict__ w1, const float* __restrict__ b1,
                      const float* __restrict__ w2, const float* __restrict__ b2,
                      float* __restrict__ h2,
                      float* __restrict__ psum, float* __restrict__ psq){
    __shared__ float W1[512], W2[512], B1[16], B2[32], GG[32], BB[32];
    __shared__ float ls[256], lq[256];
    int t = threadIdx.x;
    for (int j = t; j < 512; j += 256){ W1[j] = w1[j]; W2[j] = w2[j]; }
    if (t < 16) B1[t] = b1[t];
    if (t < 32){ B2[t] = b2[t]; GG[t] = n1g[t]; BB[t] = n1b[t]; }
    __syncthreads();
    float mu = red[0], rs = red[1];
    int n = blockIdx.x * 256 + t;
    float hv[32];
    #pragma unroll
    for (int c = 0; c < 32; ++c){
        float v = (spec[c * NSP + n] - mu) * rs * GG[c] + BB[c] + x[c * NSP + n];
        hv[c] = geluf(v);
    }
    float u[16];
    #pragma unroll
    for (int o = 0; o < 16; ++o){
        float a = B1[o];
        #pragma unroll
        for (int c = 0; c < 32; ++c) a += W1[o * 32 + c] * hv[c];
        u[o] = geluf(a);
    }
    float s_loc = 0.f, q_loc = 0.f;
    #pragma unroll
    for (int o = 0; o < 32; ++o){
        float a = B2[o];
        #pragma unroll
        for (int c = 0; c < 16; ++c) a += W2[o * 16 + c] * u[c];
        h2[o * NSP + n] = a;
        s_loc += a; q_loc += a * a;
    }
    ls[t] = s_loc; lq[t] = q_loc; __syncthreads();
    for (int off = 128; off > 0; off >>= 1){
        if (t < off){ ls[t] += ls[t + off]; lq[t] += lq[t + off]; }
        __syncthreads();
    }
    if (t == 0){ psum[blockIdx.x] = ls[0]; psq[blockIdx.x] = lq[0]; }
}

// TIN apply + QKV projections. thread per n. c-major outputs [c*NSP+n].
__global__ void k_qkv(const float* __restrict__ h2, const float* __restrict__ red,
                      const float* __restrict__ qw, const float* __restrict__ qb,
                      const float* __restrict__ kw, const float* __restrict__ vw,
                      float* __restrict__ h3, float* __restrict__ Q,
                      float* __restrict__ KH, float* __restrict__ VH){
    __shared__ float QW[1024], KW[1024], VW[1024], GA[32], BE[32], QB[32];
    int t = threadIdx.x;
    for (int j = t; j < 1024; j += 256){ QW[j] = qw[j]; KW[j] = kw[j]; VW[j] = vw[j]; }
    if (t < 32){ GA[t] = red[16 + t]; BE[t] = red[48 + t]; QB[t] = qb[t]; }
    __syncthreads();
    float mu = red[2], rs = red[3];
    int n = blockIdx.x * 256 + t;
    float hv[32];
    #pragma unroll
    for (int c = 0; c < 32; ++c){
        float v = GA[c] * ((h2[c * NSP + n] - mu) * rs) + BE[c];
        hv[c] = v;
        h3[c * NSP + n] = v;
    }
    #pragma unroll
    for (int o = 0; o < 32; ++o){
        float aq = QB[o], ak = 0.f, av = 0.f;
        #pragma unroll
        for (int c = 0; c < 32; ++c){
            float v = hv[c];
            aq += QW[o * 32 + c] * v;
            ak += KW[o * 32 + c] * v;
            av += VW[o * 32 + c] * v;
        }
        Q[o * NSP + n] = aq;
        KH[o * NSP + n] = ak;
        VH[o * NSP + n] = av;
    }
}

// attention core per (c,h): stage 3 K/V planes in LDS, 27-slot stencil + 5 memory slots,
// shared exp for zero-padded slots. out0[c*NSP + n] = softmax-weighted value sum.
__global__ void k_attn(const float* __restrict__ Q, const float* __restrict__ KH,
                       const float* __restrict__ VH,
                       const float* __restrict__ kb, const float* __restrict__ vb,
                       const float* __restrict__ mk, const float* __restrict__ mv,
                       float* __restrict__ out0){
    __shared__ float KL[3][1024], VL[3][1024];
    int bid = blockIdx.x;
    int swz = (bid & 7) * 128 + (bid >> 3);   // XCD-chunked: each XCD gets 4 consecutive channels
    int c = swz >> 5, h_ = swz & 31;
    int t = threadIdx.x;
    #pragma unroll
    for (int p = 0; p < 3; ++p){
        int hh = h_ - 1 + p;
        if ((unsigned)hh < 32u){
            const float* sk = KH + (c * 32 + hh) * 1024;
            const float* sv = VH + (c * 32 + hh) * 1024;
            for (int j = t; j < 1024; j += 256){ KL[p][j] = sk[j]; VL[p][j] = sv[j]; }
        }
    }
    float kbc = kb[c], vbc = vb[c];
    float mkv[5], mvv[5];
    #pragma unroll
    for (int j = 0; j < 5; ++j){ mkv[j] = mk[c * 5 + j]; mvv[j] = mv[c * 5 + j]; }
    float qv[4];
    #pragma unroll
    for (int i = 0; i < 4; ++i) qv[i] = Q[c * NSP + h_ * 1024 + i * 256 + t];
    __syncthreads();
    const float scale = 0.17677669529663688f; // 1/sqrt(32)
    #pragma unroll
    for (int i = 0; i < 4; ++i){
        int nl = i * 256 + t;
        int d_ = nl >> 5, w_ = nl & 31;
        float q = qv[i];
        float s = 0.f, acc = 0.f;
        #pragma unroll
        for (int j = 0; j < 5; ++j){
            float e = __expf(q * mkv[j] * scale);
            s += e; acc += e * mvv[j];
        }
        int oob = 0;
        #pragma unroll
        for (int p = 0; p < 3; ++p){
            int hh = h_ - 1 + p;
            if ((unsigned)hh >= 32u){ oob += 9; continue; }
            #pragma unroll
            for (int dj = -1; dj <= 1; ++dj){
                int dd = d_ + dj;
                if ((unsigned)dd >= 32u){ oob += 3; continue; }
                int rb = dd * 32;
                #pragma unroll
                for (int dl = -1; dl <= 1; ++dl){
                    int ww = w_ + dl;
                    if ((unsigned)ww < 32u){
                        float k = kbc + KL[p][rb + ww];
                        float v = vbc + VL[p][rb + ww];
                        float e = __expf(q * k * scale);
                        s += e; acc += e * v;
                    } else oob++;
                }
            }
        }
        float eb = __expf(q * kbc * scale);
        s += (float)oob * eb; acc += (float)oob * eb * vbc;
        out0[c * NSP + h_ * 1024 + nl] = acc / s;
    }
}

// gate + final output (+gelu(x) residual) + per-block channel partial sums. thread per n.
__global__ void k_gate(const float* __restrict__ h3, const float* __restrict__ out0,
                       const float* __restrict__ x,
                       const float* __restrict__ gw, const float* __restrict__ gb,
                       float* __restrict__ outp, float* __restrict__ mpart){
    __shared__ float GW[2048];
    __shared__ float FT[32 * 264];
    __shared__ float PS[256];
    int t = threadIdx.x;
    for (int j = t; j < 2048; j += 256) GW[j] = gw[j];
    int n = blockIdx.x * 256 + t;
    float hv[32], ov[32];
    #pragma unroll
    for (int c = 0; c < 32; ++c){ hv[c] = h3[c * NSP + n]; ov[c] = out0[c * NSP + n]; }
    __syncthreads();
    #pragma unroll
    for (int c = 0; c < 32; ++c){
        float g = gb[c];
        #pragma unroll
        for (int cc = 0; cc < 32; ++cc){
            g += GW[c * 64 + cc] * hv[cc] + GW[c * 64 + 32 + cc] * ov[cc];
        }
        g = sigmoidf_(g);
        float fin = g * ov[c] + (1.0f - g) * hv[c];
        FT[c * 264 + t] = fin;
        outp[c * NSP + n] = fin + geluf(x[c * NSP + n]);
    }
    __syncthreads();
    {
        int c8 = t >> 3, seg = t & 7;
        float s = 0.f;
        #pragma unroll
        for (int j = 0; j < 32; ++j) s += FT[c8 * 264 + seg * 32 + j];
        PS[t] = s;
    }
    __syncthreads();
    if (t < 32){
        float s = 0.f;
        #pragma unroll
        for (int j = 0; j < 8; ++j) s += PS[t * 8 + j];
        mpart[t * 128 + blockIdx.x] = s;
    }
}

// per-channel mean over 128 block partials -> red[128+c]
__global__ void k_mred(const float* __restrict__ mpart, float* __restrict__ red){
    __shared__ float ls[128];
    int c = blockIdx.x, t = threadIdx.x;
    ls[t] = mpart[c * 128 + t];
    __syncthreads();
    for (int off = 64; off > 0; off >>= 1){
        if (t < off) ls[t] += ls[t + off];
        __syncthreads();
    }
    if (t == 0) red[128 + c] = ls[0] * (1.0f / 32768.0f);
}

// GRU cell -> new_memory (f32 at offset 1048576)
__global__ void k_gru(const float* __restrict__ red, const float* __restrict__ pm,
                      const float* __restrict__ wih, const float* __restrict__ whh,
                      const float* __restrict__ bih, const float* __restrict__ bhh,
                      float* __restrict__ outp){
    __shared__ float m_in[32], gi[96], gh[96];
    int t = threadIdx.x;
    if (t < 32) m_in[t] = red[128 + t];
    __syncthreads();
    if (t < 96){
        float a = bih[t], b2 = bhh[t];
        #pragma unroll
        for (int cc = 0; cc < 32; ++cc){
            a += wih[t * 32 + cc] * m_in[cc];
            b2 += whh[t * 32 + cc] * pm[cc];
        }
        gi[t] = a; gh[t] = b2;
    }
    __syncthreads();
    if (t < 32){
        float r = sigmoidf_(gi[t] + gh[t]);
        float z = sigmoidf_(gi[32 + t] + gh[32 + t]);
        float nn = tanhf(gi[64 + t] + r * gh[64 + t]);
        float nm = (1.0f - z) * nn + z * pm[t];
        outp[1048576 + t] = nm;
    }
}

extern "C" void kernel_launch(void* const* d_in, const int* in_sizes, int n_in,
                              void* d_out, int out_size, void* d_ws, size_t ws_size,
                              hipStream_t stream){
    const float* x   = (const float*)d_in[0];
    const float* tin = (const float*)d_in[1];
    const float* pm  = (const float*)d_in[2];
    const float* wsr = (const float*)d_in[3];
    const float* wsi = (const float*)d_in[4];
    const float* n1g = (const float*)d_in[5];
    const float* n1b = (const float*)d_in[6];
    const float* mw1 = (const float*)d_in[7];
    const float* mb1 = (const float*)d_in[8];
    const float* mw2 = (const float*)d_in[9];
    const float* mb2 = (const float*)d_in[10];
    const float* tgw = (const float*)d_in[11];
    const float* tgb = (const float*)d_in[12];
    const float* tbw = (const float*)d_in[13];
    const float* tbb = (const float*)d_in[14];
    const float* qw  = (const float*)d_in[15];
    const float* qb  = (const float*)d_in[16];
    const float* kw  = (const float*)d_in[17];
    const float* kb  = (const float*)d_in[18];
    const float* vw  = (const float*)d_in[19];
    const float* vb  = (const float*)d_in[20];
    const float* mk  = (const float*)d_in[21];
    const float* mv  = (const float*)d_in[22];
    const float* gw  = (const float*)d_in[23];
    const float* gb  = (const float*)d_in[24];
    const float* wih = (const float*)d_in[25];
    const float* whh = (const float*)d_in[26];
    const float* bih = (const float*)d_in[27];
    const float* bhh = (const float*)d_in[28];

    float* ws = (float*)d_ws;
    float* Ar   = ws + 0;        // 557056
    float* Ai   = ws + 557056;   // 557056
    float* Br   = ws + 1114112;  // 557056
    float* Bi   = ws + 1671168;  // 557056
    float* spec = ws + 2228224;  // 1048576
    float* h1   = ws + 3276800;  // 1048576 (VH)
    float* h2   = ws + 4325376;  // 1048576
    float* h3   = ws + 5373952;  // 1048576
    float* red  = ws + 6422528;  // 256
    float* psum = ws + 6422784;  // 1024
    float* psq  = ws + 6423808;  // 1024
    // aliases (free by the time they're used)
    float* Qb   = Br;    // spans Br+Bi, free after k_inv
    float* KHb  = spec;  // free after k_mlp
    float* VHb  = h1;
    float* out0 = Ar;    // spans Ar+Ai, free after k_inv
    float* mpart = h2;   // 32*128, free after k_qkv

    float* outp = (float*)d_out;

    k_fwd    <<<1024, 256, 0, stream>>>(x, Br, Bi);
    k_fft_h  <<<1024, 256, 0, stream>>>(Br, Bi, Ar, Ai);
    k_modemul<<<512, 256, 0, stream>>>(Ar, Ai, wsr, wsi, Br, Bi);
    k_ifft_h <<<1024, 256, 0, stream>>>(Br, Bi, Ar, Ai);
    k_inv    <<<1024, 256, 0, stream>>>(Ar, Ai, spec, psum, psq);
    k_finalize1<<<1, 256, 0, stream>>>(psum, psq, 1024, red);
    k_mlp    <<<128, 256, 0, stream>>>(spec, x, n1g, n1b, red, mw1, mb1, mw2, mb2, h2, psum, psq);
    k_finalize2<<<1, 256, 0, stream>>>(psum, psq, 128, tin, tgw, tgb, tbw, tbb, red);
    k_qkv    <<<128, 256, 0, stream>>>(h2, red, qw, qb, kw, vw, h3, Qb, KHb, VHb);
    k_attn   <<<1024, 256, 0, stream>>>(Qb, KHb, VHb, kb, vb, mk, mv, out0);
    k_gate   <<<128, 256, 0, stream>>>(h3, out0, x, gw, gb, outp, mpart);
    k_mred   <<<32, 128, 0, stream>>>(mpart, red);
    k_gru    <<<1, 128, 0, stream>>>(red, pm, wih, whh, bih, bhh, outp);
}

// Round 9
// 191.389 us; speedup vs baseline: 1.0250x; 1.0250x over previous
//
#include <hip/hip_runtime.h>
#include <hip/hip_bf16.h>
#include <math.h>

// B=1, C=32, H=D=W=32, N=32768, modes 16^3 (z 0..15 of 17), KS=3, MEM=5
#define NSP 32768
#define NZ 17

__device__ __forceinline__ float geluf(float x){
    return 0.5f * x * (1.0f + erff(x * 0.70710678118654752f));
}
__device__ __forceinline__ float sigmoidf_(float x){
    return 1.0f / (1.0f + __expf(-x));
}

// ---------------- FFT stages (direct DFT-32) ----------------

// fused rfft along W + fft along D. x: (C,H,D,W). out Br/Bi: (C,H,Dk,17). block per (c*32+h)
__global__ void k_fwd(const float* __restrict__ x, float* __restrict__ Br, float* __restrict__ Bi){
    __shared__ float tile[32*33];
    __shared__ float ar[544], ai[544];
    __shared__ float ct[32], st[32];
    int b = blockIdx.x, t = threadIdx.x;
    if (t < 32){ float ang = 6.283185307179586477f * (float)t / 32.0f; ct[t] = cosf(ang); st[t] = sinf(ang); }
    const float* src = x + b * 1024;
    for (int j = t; j < 1024; j += 256) tile[(j & 31) * 33 + (j >> 5)] = src[j];
    __syncthreads();
    for (int idx = t; idx < 544; idx += 256){
        int d = idx / 17, z = idx - d * 17;
        float sr = 0.f, si = 0.f;
        #pragma unroll
        for (int w = 0; w < 32; ++w){
            int a = (z * w) & 31;
            float v = tile[w * 33 + d];
            sr += v * ct[a];
            si -= v * st[a];
        }
        ar[idx] = sr; ai[idx] = si;
    }
    __syncthreads();
    for (int idx = t; idx < 544; idx += 256){
        int kd = idx / 17, z = idx - kd * 17;
        float sr = 0.f, si = 0.f;
        #pragma unroll
        for (int d = 0; d < 32; ++d){
            int a = (kd * d) & 31;
            float c = ct[a], s = st[a];
            float vr = ar[d * 17 + z], vi = ai[d * 17 + z];
            sr += vr * c + vi * s;      // e^{-i}
            si += vi * c - vr * s;
        }
        Br[b * 544 + idx] = sr; Bi[b * 544 + idx] = si;
    }
}

// forward fft along H: gather h-strided. block per (c*32+d). out (C,Hk,Dk,17)
__global__ void k_fft_h(const float* __restrict__ Br, const float* __restrict__ Bi,
                        float* __restrict__ Ar, float* __restrict__ Ai){
    __shared__ float ir[544], ii[544];
    __shared__ float ct[32], st[32];
    int b = blockIdx.x, t = threadIdx.x;
    int c = b >> 5, d = b & 31;
    if (t < 32){ float ang = 6.283185307179586477f * (float)t / 32.0f; ct[t] = cosf(ang); st[t] = sinf(ang); }
    for (int j = t; j < 544; j += 256){
        int h = j / 17, z = j - h * 17;
        int g = ((c * 32 + h) * 32 + d) * NZ + z;
        ir[j] = Br[g]; ii[j] = Bi[g];
    }
    __syncthreads();
    for (int idx = t; idx < 544; idx += 256){
        int kh = idx / 17, z = idx - kh * 17;
        float sr = 0.f, si = 0.f;
        #pragma unroll
        for (int h = 0; h < 32; ++h){
            int a = (kh * h) & 31;
            float c2 = ct[a], s2 = st[a];
            float vr = ir[h * 17 + z], vi = ii[h * 17 + z];
            sr += vr * c2 + vi * s2;
            si += vi * c2 - vr * s2;
        }
        int g = ((c * 32 + kh) * 32 + d) * NZ + z;
        Ar[g] = sr; Ai[g] = si;
    }
}

// spectral multiply. Xr/Xi: (C,Hk,Dk,17). W: (4,Ci,Co,16,16,16). Out Or/Oi, z=16 zeroed.
// block = ((corner*32 + o)*4 + q): per (i,array) reads a contiguous 4KB quarter-row;
// q-adjacent blocks stream the 4 quarters concurrently (~16KB effective granule).
// x read per-thread from L2 (reused by 32 o-blocks). No LDS, no syncthreads.
__global__ void k_modemul(const float* __restrict__ Xr, const float* __restrict__ Xi,
                          const float* __restrict__ Wr, const float* __restrict__ Wi,
                          float* __restrict__ Or, float* __restrict__ Oi){
    int b = blockIdx.x;
    int q = b & 3;
    int o = (b >> 2) & 31;
    int corner = b >> 7;
    int t = threadIdx.x;
    int m = q * 1024 + t * 4;              // this thread's 4 consecutive modes
    int xm = m >> 8, ym = (m >> 4) & 15, zm = m & 15;
    int xg = xm + ((corner & 1) << 4);
    int y  = ym + ((corner >> 1) << 4);
    // zero z=16 plane for this block's (o, xm-range of 4, all 16 y), both arrays
    if (t < 128){
        int xl = t >> 5;           // 0..3
        int arr = (t >> 4) & 1;
        int yl = t & 15;
        int xgz = q * 4 + xl + ((corner & 1) << 4);
        int yz = yl + ((corner >> 1) << 4);
        int g = ((o * 32 + xgz) * 32 + yz) * NZ + 16;
        if (arr == 0) Or[g] = 0.f; else Oi[g] = 0.f;
    }
    size_t xoff = (size_t)(xg * 32 + y) * NZ + zm;            // + i*32*32*17
    const float* wr = Wr + (size_t)((corner * 32) * 32 + o) * 4096 + m;   // + i*32*4096
    const float* wi = Wi + (size_t)((corner * 32) * 32 + o) * 4096 + m;
    float ar0=0.f, ar1=0.f, ar2=0.f, ar3=0.f;
    float ai0=0.f, ai1=0.f, ai2=0.f, ai3=0.f;
    #pragma unroll 4
    for (int i = 0; i < 32; ++i){
        float4 w4r = *(const float4*)(wr + (size_t)i * 131072);
        float4 w4i = *(const float4*)(wi + (size_t)i * 131072);
        const float* pxr = Xr + (size_t)i * 17408 + xoff;
        const float* pxi = Xi + (size_t)i * 17408 + xoff;
        float xr0 = pxr[0], xr1 = pxr[1], xr2 = pxr[2], xr3 = pxr[3];
        float xi0 = pxi[0], xi1 = pxi[1], xi2 = pxi[2], xi3 = pxi[3];
        ar0 += w4r.x * xr0 - w4i.x * xi0;  ai0 += w4r.x * xi0 + w4i.x * xr0;
        ar1 += w4r.y * xr1 - w4i.y * xi1;  ai1 += w4r.y * xi1 + w4i.y * xr1;
        ar2 += w4r.z * xr2 - w4i.z * xi2;  ai2 += w4r.z * xi2 + w4i.z * xr2;
        ar3 += w4r.w * xr3 - w4i.w * xi3;  ai3 += w4r.w * xi3 + w4i.w * xr3;
    }
    int g = ((o * 32 + xg) * 32 + y) * NZ + zm;
    Or[g + 0] = ar0; Or[g + 1] = ar1; Or[g + 2] = ar2; Or[g + 3] = ar3;
    Oi[g + 0] = ai0; Oi[g + 1] = ai1; Oi[g + 2] = ai2; Oi[g + 3] = ai3;
}

// inverse fft along H. block per (c*32+y). in (C,Hk,Dk,17) -> (C,H,Dk,17)
__global__ void k_ifft_h(const float* __restrict__ Br, const float* __restrict__ Bi,
                         float* __restrict__ Ar, float* __restrict__ Ai){
    __shared__ float ir[544], ii[544];
    __shared__ float ct[32], st[32];
    int b = blockIdx.x, t = threadIdx.x;
    int c = b >> 5, y = b & 31;
    if (t < 32){ float ang = 6.283185307179586477f * (float)t / 32.0f; ct[t] = cosf(ang); st[t] = sinf(ang); }
    for (int j = t; j < 544; j += 256){
        int xk = j / 17, z = j - xk * 17;
        int g = ((c * 32 + xk) * 32 + y) * NZ + z;
        ir[j] = Br[g]; ii[j] = Bi[g];
    }
    __syncthreads();
    for (int idx = t; idx < 544; idx += 256){
        int h = idx / 17, z = idx - h * 17;
        float sr = 0.f, si = 0.f;
        #pragma unroll
        for (int k = 0; k < 32; ++k){
            int a = (k * h) & 31;
            float c2 = ct[a], s2 = st[a];
            float vr = ir[k * 17 + z], vi = ii[k * 17 + z];
            sr += vr * c2 - vi * s2;    // e^{+i}
            si += vr * s2 + vi * c2;
        }
        int g = ((c * 32 + h) * 32 + y) * NZ + z;
        Ar[g] = sr; Ai[g] = si;
    }
}

// fused inverse fft along D + irfft along W + GN1 stat partials. block per (c*32+h).
__global__ void k_inv(const float* __restrict__ Ar, const float* __restrict__ Ai,
                      float* __restrict__ spec,
                      float* __restrict__ psum, float* __restrict__ psq){
    __shared__ float ir[544], ii[544];
    __shared__ float cr[544], ci[544];
    __shared__ float ct[32], st[32];
    __shared__ float ls[256], lq[256];
    int b = blockIdx.x, t = threadIdx.x;
    if (t < 32){ float ang = 6.283185307179586477f * (float)t / 32.0f; ct[t] = cosf(ang); st[t] = sinf(ang); }
    const float* pr = Ar + b * 544;
    const float* pi = Ai + b * 544;
    for (int j = t; j < 544; j += 256){ ir[j] = pr[j]; ii[j] = pi[j]; }
    __syncthreads();
    for (int idx = t; idx < 544; idx += 256){
        int d = idx / 17, z = idx - d * 17;
        float sr = 0.f, si = 0.f;
        #pragma unroll
        for (int k = 0; k < 32; ++k){
            int a = (k * d) & 31;
            float c2 = ct[a], s2 = st[a];
            float vr = ir[k * 17 + z], vi = ii[k * 17 + z];
            sr += vr * c2 - vi * s2;
            si += vr * s2 + vi * c2;
        }
        cr[idx] = sr; ci[idx] = si;
    }
    __syncthreads();
    const float inv = 1.0f / 32768.0f;
    float s_loc = 0.f, q_loc = 0.f;
    for (int idx = t; idx < 1024; idx += 256){
        int d = idx >> 5, w = idx & 31;
        float s = cr[d * 17 + 0] + ((w & 1) ? -cr[d * 17 + 16] : cr[d * 17 + 16]);
        #pragma unroll
        for (int z = 1; z < 16; ++z){
            int a = (z * w) & 31;
            s += 2.0f * (cr[d * 17 + z] * ct[a] - ci[d * 17 + z] * st[a]);
        }
        s *= inv;
        spec[b * 1024 + idx] = s;
        s_loc += s; q_loc += s * s;
    }
    ls[t] = s_loc; lq[t] = q_loc; __syncthreads();
    for (int off = 128; off > 0; off >>= 1){
        if (t < off){ ls[t] += ls[t + off]; lq[t] += lq[t + off]; }
        __syncthreads();
    }
    if (t == 0){ psum[b] = ls[0]; psq[b] = lq[0]; }
}

// ---------------- reductions / elementwise ----------------

__global__ void k_finalize1(const float* __restrict__ psum, const float* __restrict__ psq,
                            int n, float* __restrict__ red){
    __shared__ float ls[256], lq[256];
    int t = threadIdx.x;
    float s = 0.f, q = 0.f;
    for (int j = t; j < n; j += 256){ s += psum[j]; q += psq[j]; }
    ls[t] = s; lq[t] = q; __syncthreads();
    for (int off = 128; off > 0; off >>= 1){
        if (t < off){ ls[t] += ls[t + off]; lq[t] += lq[t + off]; }
        __syncthreads();
    }
    if (t == 0){
        float mu = ls[0] * (1.0f / 1048576.0f);
        float var = lq[0] * (1.0f / 1048576.0f) - mu * mu;
        red[0] = mu; red[1] = rsqrtf(var + 1e-5f);
    }
}

// GN2 finalize + gamma/beta from t
__global__ void k_finalize2(const float* __restrict__ psum, const float* __restrict__ psq,
                            int n, const float* __restrict__ tin,
                            const float* __restrict__ tgw, const float* __restrict__ tgb,
                            const float* __restrict__ tbw, const float* __restrict__ tbb,
                            float* __restrict__ red){
    __shared__ float ls[256], lq[256];
    int t = threadIdx.x;
    float s = 0.f, q = 0.f;
    for (int j = t; j < n; j += 256){ s += psum[j]; q += psq[j]; }
    ls[t] = s; lq[t] = q; __syncthreads();
    for (int off = 128; off > 0; off >>= 1){
        if (t < off){ ls[t] += ls[t + off]; lq[t] += lq[t + off]; }
        __syncthreads();
    }
    if (t == 0){
        float mu = ls[0] * (1.0f / 1048576.0f);
        float var = lq[0] * (1.0f / 1048576.0f) - mu * mu;
        red[2] = mu; red[3] = rsqrtf(var + 1e-5f);
    }
    if (t < 64){
        int o = t & 31;
        const float* w = (t < 32) ? tgw : tbw;
        const float* bi = (t < 32) ? tgb : tbb;
        float a = bi[o];
        #pragma unroll
        for (int c = 0; c < 32; ++c) a += w[o * 32 + c] * tin[c];
        red[(t < 32 ? 16 : 48) + o] = a;
    }
}

// fused GN1-apply + pointwise MLP (32 -> 16 gelu -> 32) + GN2 stat partials. thread per n.
__global__ void k_mlp(const float* __restrict__ spec, const float* __restrict__ x,
                      const float* __restrict__ n1g, const float* __restrict__ n1b,
                      const float* __restrict__ red,
                      const float* __restrict__ w1, const float* __restrict__ b1,
                      const float* __restrict__ w2, const float* __restrict__ b2,
                      float* __restrict__ h2,
                      float* __restrict__ psum, float* __restrict__ psq){
    __shared__ float W1[512], W2[512], B1[16], B2[32], GG[32], BB[32];
    __shared__ float ls[256], lq[256];
    int t = threadIdx.x;
    for (int j = t; j < 512; j += 256){ W1[j] = w1[j]; W2[j] = w2[j]; }
    if (t < 16) B1[t] = b1[t];
    if (t < 32){ B2[t] = b2[t]; GG[t] = n1g[t]; BB[t] = n1b[t]; }
    __syncthreads();
    float mu = red[0], rs = red[1];
    int n = blockIdx.x * 256 + t;
    float hv[32];
    #pragma unroll
    for (int c = 0; c < 32; ++c){
        float v = (spec[c * NSP + n] - mu) * rs * GG[c] + BB[c] + x[c * NSP + n];
        hv[c] = geluf(v);
    }
    float u[16];
    #pragma unroll
    for (int o = 0; o < 16; ++o){
        float a = B1[o];
        #pragma unroll
        for (int c = 0; c < 32; ++c) a += W1[o * 32 + c] * hv[c];
        u[o] = geluf(a);
    }
    float s_loc = 0.f, q_loc = 0.f;
    #pragma unroll
    for (int o = 0; o < 32; ++o){
        float a = B2[o];
        #pragma unroll
        for (int c = 0; c < 16; ++c) a += W2[o * 16 + c] * u[c];
        h2[o * NSP + n] = a;
        s_loc += a; q_loc += a * a;
    }
    ls[t] = s_loc; lq[t] = q_loc; __syncthreads();
    for (int off = 128; off > 0; off >>= 1){
        if (t < off){ ls[t] += ls[t + off]; lq[t] += lq[t + off]; }
        __syncthreads();
    }
    if (t == 0){ psum[blockIdx.x] = ls[0]; psq[blockIdx.x] = lq[0]; }
}

// TIN apply + QKV projections. thread per n. c-major outputs [c*NSP+n].
__global__ void k_qkv(const float* __restrict__ h2, const float* __restrict__ red,
                      const float* __restrict__ qw, const float* __restrict__ qb,
                      const float* __restrict__ kw, const float* __restrict__ vw,
                      float* __restrict__ h3, float* __restrict__ Q,
                      float* __restrict__ KH, float* __restrict__ VH){
    __shared__ float QW[1024], KW[1024], VW[1024], GA[32], BE[32], QB[32];
    int t = threadIdx.x;
    for (int j = t; j < 1024; j += 256){ QW[j] = qw[j]; KW[j] = kw[j]; VW[j] = vw[j]; }
    if (t < 32){ GA[t] = red[16 + t]; BE[t] = red[48 + t]; QB[t] = qb[t]; }
    __syncthreads();
    float mu = red[2], rs = red[3];
    int n = blockIdx.x * 256 + t;
    float hv[32];
    #pragma unroll
    for (int c = 0; c < 32; ++c){
        float v = GA[c] * ((h2[c * NSP + n] - mu) * rs) + BE[c];
        hv[c] = v;
        h3[c * NSP + n] = v;
    }
    #pragma unroll
    for (int o = 0; o < 32; ++o){
        float aq = QB[o], ak = 0.f, av = 0.f;
        #pragma unroll
        for (int c = 0; c < 32; ++c){
            float v = hv[c];
            aq += QW[o * 32 + c] * v;
            ak += KW[o * 32 + c] * v;
            av += VW[o * 32 + c] * v;
        }
        Q[o * NSP + n] = aq;
        KH[o * NSP + n] = ak;
        VH[o * NSP + n] = av;
    }
}

// attention core per (c,h): stage 3 K/V planes in LDS, 27-slot stencil + 5 memory slots,
// shared exp for zero-padded slots. out0[c*NSP + n] = softmax-weighted value sum.
__global__ void k_attn(const float* __restrict__ Q, const float* __restrict__ KH,
                       const float* __restrict__ VH,
                       const float* __restrict__ kb, const float* __restrict__ vb,
                       const float* __restrict__ mk, const float* __restrict__ mv,
                       float* __restrict__ out0){
    __shared__ float KL[3][1024], VL[3][1024];
    int bid = blockIdx.x;
    int swz = (bid & 7) * 128 + (bid >> 3);   // XCD-chunked: each XCD gets 4 consecutive channels
    int c = swz >> 5, h_ = swz & 31;
    int t = threadIdx.x;
    #pragma unroll
    for (int p = 0; p < 3; ++p){
        int hh = h_ - 1 + p;
        if ((unsigned)hh < 32u){
            const float* sk = KH + (c * 32 + hh) * 1024;
            const float* sv = VH + (c * 32 + hh) * 1024;
            for (int j = t; j < 1024; j += 256){ KL[p][j] = sk[j]; VL[p][j] = sv[j]; }
        }
    }
    float kbc = kb[c], vbc = vb[c];
    float mkv[5], mvv[5];
    #pragma unroll
    for (int j = 0; j < 5; ++j){ mkv[j] = mk[c * 5 + j]; mvv[j] = mv[c * 5 + j]; }
    float qv[4];
    #pragma unroll
    for (int i = 0; i < 4; ++i) qv[i] = Q[c * NSP + h_ * 1024 + i * 256 + t];
    __syncthreads();
    const float scale = 0.17677669529663688f; // 1/sqrt(32)
    #pragma unroll
    for (int i = 0; i < 4; ++i){
        int nl = i * 256 + t;
        int d_ = nl >> 5, w_ = nl & 31;
        float q = qv[i];
        float s = 0.f, acc = 0.f;
        #pragma unroll
        for (int j = 0; j < 5; ++j){
            float e = __expf(q * mkv[j] * scale);
            s += e; acc += e * mvv[j];
        }
        int oob = 0;
        #pragma unroll
        for (int p = 0; p < 3; ++p){
            int hh = h_ - 1 + p;
            if ((unsigned)hh >= 32u){ oob += 9; continue; }
            #pragma unroll
            for (int dj = -1; dj <= 1; ++dj){
                int dd = d_ + dj;
                if ((unsigned)dd >= 32u){ oob += 3; continue; }
                int rb = dd * 32;
                #pragma unroll
                for (int dl = -1; dl <= 1; ++dl){
                    int ww = w_ + dl;
                    if ((unsigned)ww < 32u){
                        float k = kbc + KL[p][rb + ww];
                        float v = vbc + VL[p][rb + ww];
                        float e = __expf(q * k * scale);
                        s += e; acc += e * v;
                    } else oob++;
                }
            }
        }
        float eb = __expf(q * kbc * scale);
        s += (float)oob * eb; acc += (float)oob * eb * vbc;
        out0[c * NSP + h_ * 1024 + nl] = acc / s;
    }
}

// gate + final output (+gelu(x) residual) + per-block channel partial sums. thread per n.
__global__ void k_gate(const float* __restrict__ h3, const float* __restrict__ out0,
                       const float* __restrict__ x,
                       const float* __restrict__ gw, const float* __restrict__ gb,
                       float* __restrict__ outp, float* __restrict__ mpart){
    __shared__ float GW[2048];
    __shared__ float FT[32 * 264];
    __shared__ float PS[256];
    int t = threadIdx.x;
    for (int j = t; j < 2048; j += 256) GW[j] = gw[j];
    int n = blockIdx.x * 256 + t;
    float hv[32], ov[32];
    #pragma unroll
    for (int c = 0; c < 32; ++c){ hv[c] = h3[c * NSP + n]; ov[c] = out0[c * NSP + n]; }
    __syncthreads();
    #pragma unroll
    for (int c = 0; c < 32; ++c){
        float g = gb[c];
        #pragma unroll
        for (int cc = 0; cc < 32; ++cc){
            g += GW[c * 64 + cc] * hv[cc] + GW[c * 64 + 32 + cc] * ov[cc];
        }
        g = sigmoidf_(g);
        float fin = g * ov[c] + (1.0f - g) * hv[c];
        FT[c * 264 + t] = fin;
        outp[c * NSP + n] = fin + geluf(x[c * NSP + n]);
    }
    __syncthreads();
    {
        int c8 = t >> 3, seg = t & 7;
        float s = 0.f;
        #pragma unroll
        for (int j = 0; j < 32; ++j) s += FT[c8 * 264 + seg * 32 + j];
        PS[t] = s;
    }
    __syncthreads();
    if (t < 32){
        float s = 0.f;
        #pragma unroll
        for (int j = 0; j < 8; ++j) s += PS[t * 8 + j];
        mpart[t * 128 + blockIdx.x] = s;
    }
}

// per-channel mean over 128 block partials -> red[128+c]
__global__ void k_mred(const float* __restrict__ mpart, float* __restrict__ red){
    __shared__ float ls[128];
    int c = blockIdx.x, t = threadIdx.x;
    ls[t] = mpart[c * 128 + t];
    __syncthreads();
    for (int off = 64; off > 0; off >>= 1){
        if (t < off) ls[t] += ls[t + off];
        __syncthreads();
    }
    if (t == 0) red[128 + c] = ls[0] * (1.0f / 32768.0f);
}

// GRU cell -> new_memory (f32 at offset 1048576)
__global__ void k_gru(const float* __restrict__ red, const float* __restrict__ pm,
                      const float* __restrict__ wih, const float* __restrict__ whh,
                      const float* __restrict__ bih, const float* __restrict__ bhh,
                      float* __restrict__ outp){
    __shared__ float m_in[32], gi[96], gh[96];
    int t = threadIdx.x;
    if (t < 32) m_in[t] = red[128 + t];
    __syncthreads();
    if (t < 96){
        float a = bih[t], b2 = bhh[t];
        #pragma unroll
        for (int cc = 0; cc < 32; ++cc){
            a += wih[t * 32 + cc] * m_in[cc];
            b2 += whh[t * 32 + cc] * pm[cc];
        }
        gi[t] = a; gh[t] = b2;
    }
    __syncthreads();
    if (t < 32){
        float r = sigmoidf_(gi[t] + gh[t]);
        float z = sigmoidf_(gi[32 + t] + gh[32 + t]);
        float nn = tanhf(gi[64 + t] + r * gh[64 + t]);
        float nm = (1.0f - z) * nn + z * pm[t];
        outp[1048576 + t] = nm;
    }
}

extern "C" void kernel_launch(void* const* d_in, const int* in_sizes, int n_in,
                              void* d_out, int out_size, void* d_ws, size_t ws_size,
                              hipStream_t stream){
    const float* x   = (const float*)d_in[0];
    const float* tin = (const float*)d_in[1];
    const float* pm  = (const float*)d_in[2];
    const float* wsr = (const float*)d_in[3];
    const float* wsi = (const float*)d_in[4];
    const float* n1g = (const float*)d_in[5];
    const float* n1b = (const float*)d_in[6];
    const float* mw1 = (const float*)d_in[7];
    const float* mb1 = (const float*)d_in[8];
    const float* mw2 = (const float*)d_in[9];
    const float* mb2 = (const float*)d_in[10];
    const float* tgw = (const float*)d_in[11];
    const float* tgb = (const float*)d_in[12];
    const float* tbw = (const float*)d_in[13];
    const float* tbb = (const float*)d_in[14];
    const float* qw  = (const float*)d_in[15];
    const float* qb  = (const float*)d_in[16];
    const float* kw  = (const float*)d_in[17];
    const float* kb  = (const float*)d_in[18];
    const float* vw  = (const float*)d_in[19];
    const float* vb  = (const float*)d_in[20];
    const float* mk  = (const float*)d_in[21];
    const float* mv  = (const float*)d_in[22];
    const float* gw  = (const float*)d_in[23];
    const float* gb  = (const float*)d_in[24];
    const float* wih = (const float*)d_in[25];
    const float* whh = (const float*)d_in[26];
    const float* bih = (const float*)d_in[27];
    const float* bhh = (const float*)d_in[28];

    float* ws = (float*)d_ws;
    float* Ar   = ws + 0;        // 557056
    float* Ai   = ws + 557056;   // 557056
    float* Br   = ws + 1114112;  // 557056
    float* Bi   = ws + 1671168;  // 557056
    float* spec = ws + 2228224;  // 1048576
    float* h1   = ws + 3276800;  // 1048576 (VH)
    float* h2   = ws + 4325376;  // 1048576
    float* h3   = ws + 5373952;  // 1048576
    float* red  = ws + 6422528;  // 256
    float* psum = ws + 6422784;  // 1024
    float* psq  = ws + 6423808;  // 1024
    // aliases (free by the time they're used)
    float* Qb   = Br;    // spans Br+Bi, free after k_inv
    float* KHb  = spec;  // free after k_mlp
    float* VHb  = h1;
    float* out0 = Ar;    // spans Ar+Ai, free after k_inv
    float* mpart = h2;   // 32*128, free after k_qkv

    float* outp = (float*)d_out;

    k_fwd    <<<1024, 256, 0, stream>>>(x, Br, Bi);
    k_fft_h  <<<1024, 256, 0, stream>>>(Br, Bi, Ar, Ai);
    k_modemul<<<512, 256, 0, stream>>>(Ar, Ai, wsr, wsi, Br, Bi);
    k_ifft_h <<<1024, 256, 0, stream>>>(Br, Bi, Ar, Ai);
    k_inv    <<<1024, 256, 0, stream>>>(Ar, Ai, spec, psum, psq);
    k_finalize1<<<1, 256, 0, stream>>>(psum, psq, 1024, red);
    k_mlp    <<<128, 256, 0, stream>>>(spec, x, n1g, n1b, red, mw1, mb1, mw2, mb2, h2, psum, psq);
    k_finalize2<<<1, 256, 0, stream>>>(psum, psq, 128, tin, tgw, tgb, tbw, tbb, red);
    k_qkv    <<<128, 256, 0, stream>>>(h2, red, qw, qb, kw, vw, h3, Qb, KHb, VHb);
    k_attn   <<<1024, 256, 0, stream>>>(Qb, KHb, VHb, kb, vb, mk, mv, out0);
    k_gate   <<<128, 256, 0, stream>>>(h3, out0, x, gw, gb, outp, mpart);
    k_mred   <<<32, 128, 0, stream>>>(mpart, red);
    k_gru    <<<1, 128, 0, stream>>>(red, pm, wih, whh, bih, bhh, outp);
}